// Round 15
// baseline (108.395 us; speedup 1.0000x reference)
//
#include <hip/hip_runtime.h>

#define T_SEQ 50
#define BATCH 8192
#define INPUT 33
#define HID   256
#define BTILE 32
#define NTH   1024   // 16 waves, 1 block/CU, 4 waves/SIMD

typedef __attribute__((ext_vector_type(8))) short short8;
typedef __attribute__((ext_vector_type(4))) short short4v;
typedef __attribute__((ext_vector_type(4))) float float4v;

// bf16 h / x staging, double-buffered (units: shorts). 43 KB total.
#define H_STRIDE 264                       // 256 + 8 pad (2-way aliasing = free)
#define X_STRIDE 72                        // 64 + 8
#define H0 0
#define H1 (BTILE * H_STRIDE)              // 8448
#define X0 (2 * BTILE * H_STRIDE)          // 16896
#define X1 (X0 + BTILE * X_STRIDE)         // 19200
#define LDS_SHORTS (X1 + BTILE * X_STRIDE) // 21504 shorts = 43008 B

__device__ __forceinline__ short f2bf(float v) {   // RNE f32 -> bf16 bits
  unsigned u = __builtin_bit_cast(unsigned, v);
  u = (u + 0x7FFFu + ((u >> 16) & 1u)) >> 16;
  return (short)u;
}
__device__ __forceinline__ float bf2f(short s) {
  return __builtin_bit_cast(float, ((unsigned)(unsigned short)s) << 16);
}

#define MFMA(a, b, c) __builtin_amdgcn_mfma_f32_16x16x32_bf16(a, b, c, 0, 0, 0)

// One step, 16-wave variant of the 95.1-us R14 structure. Per wave: 16 j-cols
// (c0 = wave*16), 20 MFMA, 8 b16 h-restage writes, 2-row bf16 readback + 2
// NONTEMPORAL dwordx4 output stores. One lgkm-only barrier; no vmcnt waits.
#define CSTEP(HR, XR, HW, XW, T)                                              \
  {                                                                           \
    float xp0 = 0.f, xp1 = 0.f;                                               \
    const bool more = (T) + 1 < T_SEQ;                                        \
    if (more) {                                                               \
      const float* xt1 = xpf + (size_t)((T) + 1) * xstep;                     \
      xp0 = xt1[e0];                                                          \
      if (p1) xp1 = xt1[e1];                                                  \
    }                                                                         \
    float4v acc[2];                                                           \
    _Pragma("unroll") for (int m = 0; m < 2; ++m)                             \
      _Pragma("unroll") for (int i = 0; i < 4; ++i)                           \
        acc[m][i] = hst[m][i] + bc;                                           \
    const short* hb = lds + (HR);                                             \
    const short* xb = lds + (XR);                                             \
    _Pragma("unroll") for (int ks = 0; ks < 8; ++ks) {                        \
      const int k = ks * 32 + kq * 8;                                         \
      short8 a0 = *(const short8*)(hb + colA * H_STRIDE + k);                 \
      short8 a1 = *(const short8*)(hb + (16 + colA) * H_STRIDE + k);          \
      acc[0] = MFMA(a0, wf[ks], acc[0]);                                      \
      acc[1] = MFMA(a1, wf[ks], acc[1]);                                      \
    }                                                                         \
    _Pragma("unroll") for (int kb = 0; kb < 2; ++kb) {                        \
      const int k = kb * 32 + kq * 8;                                         \
      short8 a0 = *(const short8*)(xb + colA * X_STRIDE + k);                 \
      short8 a1 = *(const short8*)(xb + (16 + colA) * X_STRIDE + k);          \
      acc[0] = MFMA(a0, win[kb], acc[0]);                                     \
      acc[1] = MFMA(a1, win[kb], acc[1]);                                     \
    }                                                                         \
    _Pragma("unroll") for (int m = 0; m < 2; ++m)                             \
      _Pragma("unroll") for (int i = 0; i < 4; ++i) {                         \
        float hn = fmaxf(0.5f * acc[m][i], 0.0f);                             \
        hst[m][i] = hn;                                                       \
        lds[(HW) + (m * 16 + kq * 4 + i) * H_STRIDE + c0 + colA] =            \
            f2bf(hn);                                                         \
      }                                                                       \
    if (more) {                                                               \
      lds[(XW) + r0 * X_STRIDE + c0x] = f2bf(xp0);                            \
      if (p1) lds[(XW) + r1 * X_STRIDE + c1x] = f2bf(xp1);                    \
    }                                                                         \
    __builtin_amdgcn_sched_barrier(0);                                        \
    asm volatile("s_waitcnt lgkmcnt(0)" ::: "memory");                        \
    __builtin_amdgcn_s_barrier();                                             \
    __builtin_amdgcn_sched_barrier(0);                                        \
    _Pragma("unroll") for (int j = 0; j < 2; ++j) {                           \
      short4v hv = *(const short4v*)(lds + (HW) + (2 * wave + j) * H_STRIDE + 4 * lane); \
      float4v ov;                                                             \
      ov[0] = bf2f(hv[0]); ov[1] = bf2f(hv[1]);                               \
      ov[2] = bf2f(hv[2]); ov[3] = bf2f(hv[3]);                               \
      __builtin_nontemporal_store(ov, (float4v*)(outg + j * HID));            \
    }                                                                         \
    outg += outstep;                                                          \
  }

__global__ __launch_bounds__(NTH, 2)
void ctrnn_kernel(const float* __restrict__ x, const int* __restrict__ sub_id,
                  const float* __restrict__ gates, const float* __restrict__ W_in,
                  const float* __restrict__ b_in, const float* __restrict__ W_h,
                  const float* __restrict__ b_h, float* __restrict__ out)
{
  __shared__ short lds[LDS_SHORTS];
  const int tid  = threadIdx.x;
  const int lane = tid & 63;
  const int wave = tid >> 6;    // 0..15
  const int colA = lane & 15;   // A-row (batch) / C-col within tile
  const int kq   = lane >> 4;   // k-quadrant / C-row group
  const int c0   = wave * 16;   // wave's hidden-j base (16 waves x 16 j)
  const int brow0 = blockIdx.x * BTILE;

  const int sid = sub_id[0];
  const float* grow = gates + sid * HID;

  // ---- zero h/x staging (h0 = 0; x pad columns stay 0 forever) ----
  {
    int* ldsi = (int*)lds;
    for (int i = tid; i < LDS_SHORTS / 2; i += NTH) ldsi[i] = 0;
  }

  // ---- t-invariant operands in REGISTERS (per wave: 16 j-cols) ----
  short8 wf[8];    // B-fragments of W_h' = diag(g)*W_h  (32 VGPRs)
  short8 win[2];   // B-fragments of W_in (zero-padded K=64)
  float  bc;
  {
    const int col = c0 + colA;
    const float g = grow[col];
    #pragma unroll
    for (int ks = 0; ks < 8; ++ks) {
      const float* wp = W_h + col * HID + ks * 32 + kq * 8;
      float4v w0 = *(const float4v*)wp;
      float4v w1 = *(const float4v*)(wp + 4);
      short8 f;
      f[0] = f2bf(g * w0[0]); f[1] = f2bf(g * w0[1]);
      f[2] = f2bf(g * w0[2]); f[3] = f2bf(g * w0[3]);
      f[4] = f2bf(g * w1[0]); f[5] = f2bf(g * w1[1]);
      f[6] = f2bf(g * w1[2]); f[7] = f2bf(g * w1[3]);
      wf[ks] = f;
    }
    #pragma unroll
    for (int kb = 0; kb < 2; ++kb) {
      short8 f;
      #pragma unroll
      for (int j = 0; j < 8; ++j) {
        int kk = kb * 32 + kq * 8 + j;
        f[j] = (kk < INPUT) ? f2bf(W_in[col * INPUT + kk]) : (short)0;
      }
      win[kb] = f;
    }
    bc = b_in[col] + g * b_h[col];
  }

  __syncthreads();   // zero-fill complete before x0 staging

  // ---- stage x_0 into buffer 0 ----
  {
    const float* xt = x + (size_t)brow0 * INPUT;
    for (int e = tid; e < BTILE * INPUT; e += NTH) {
      int r = e / INPUT, c = e - r * INPUT;
      lds[X0 + r * X_STRIDE + c] = f2bf(xt[e]);
    }
  }

  // x-prefetch invariants (1056 elems over 1024 threads, 2 rounds)
  const int e0 = tid, e1 = tid + NTH;
  const int r0 = e0 / INPUT, c0x = e0 - r0 * INPUT;
  const int r1 = e1 / INPUT, c1x = e1 - r1 * INPUT;
  const bool p1 = (e1 < BTILE * INPUT);

  // persistent f32 h master at MFMA C-layout: hst[m][i] =
  //   h[b = brow0 + m*16 + kq*4 + i][j = c0 + colA]
  float4v hst[2];
  #pragma unroll
  for (int m = 0; m < 2; ++m)
    #pragma unroll
    for (int i = 0; i < 4; ++i) hst[m][i] = 0.0f;

  // coalesced store base: wave w owns tile rows 2w, 2w+1; lane covers 16B
  float* outg = out + (size_t)(brow0 + 2 * wave) * HID + 4 * lane;
  const int outstep = BATCH * HID;
  const float* xpf = x + (size_t)brow0 * INPUT;
  const int xstep = BATCH * INPUT;

  __syncthreads();   // x0 staged; h0 zeroed

  #pragma unroll 1
  for (int t2 = 0; t2 < T_SEQ / 2; ++t2) {
    CSTEP(H0, X0, H1, X1, 2 * t2);       // even: read buf0, write buf1
    CSTEP(H1, X1, H0, X0, 2 * t2 + 1);   // odd:  read buf1, write buf0
  }

  // h_last == output[T-1]; read back from H0 (written by step T-1)
  {
    float* hl = out + (size_t)T_SEQ * BATCH * HID +
                (size_t)(brow0 + 2 * wave) * HID + 4 * lane;
    #pragma unroll
    for (int j = 0; j < 2; ++j) {
      short4v hv = *(const short4v*)(lds + H0 + (2 * wave + j) * H_STRIDE + 4 * lane);
      float4v ov;
      ov[0] = bf2f(hv[0]); ov[1] = bf2f(hv[1]);
      ov[2] = bf2f(hv[2]); ov[3] = bf2f(hv[3]);
      __builtin_nontemporal_store(ov, (float4v*)(hl + j * HID));
    }
  }
}

extern "C" void kernel_launch(void* const* d_in, const int* in_sizes, int n_in,
                              void* d_out, int out_size, void* d_ws, size_t ws_size,
                              hipStream_t stream) {
  const float* x    = (const float*)d_in[0];
  const int*   sid  = (const int*)  d_in[1];
  const float* gts  = (const float*)d_in[2];
  const float* W_in = (const float*)d_in[3];
  const float* b_in = (const float*)d_in[4];
  const float* W_h  = (const float*)d_in[5];
  const float* b_h  = (const float*)d_in[6];
  float* out = (float*)d_out;

  ctrnn_kernel<<<BATCH / BTILE, NTH, 0, stream>>>(x, sid, gts, W_in, b_in, W_h, b_h, out);
}